// Round 2
// baseline (50265.485 us; speedup 1.0000x reference)
//
#include <hip/hip_runtime.h>

// Problem sizes (fixed by reference)
#define BB 32
#define TT 512
#define DD 512
#define HH 512
#define LL 4
#define HB (HH * BB)           // 16384
#define NWG 192
#define TPB 512

// ws: data floats then flag/counter slots (memset to 0 by host each call)
#define STATE_FLOATS (LL * 2 * HB)              // 131072
#define GATE_FLOATS  (3 * LL * HB)              // 196608
#define DATA_FLOATS  (STATE_FLOATS + GATE_FLOATS)
#define FLAG_STRIDE  64                          // 256 B per counter slot
#define NFLAG        209                         // keep prior ws footprint
#define FLAGS_BYTES  ((unsigned long long)NFLAG * FLAG_STRIDE * 4ull)
#define WS_NEED_BYTES ((unsigned long long)DATA_FLOATS * 4ull + FLAGS_BYTES)
#define LDS_BYTES 139264       // 128 KB resident weights + 8 KB reduce scratch

// ---- self-timed dataflow, split per-gate counters ----
// CNT(i,g): g=0 z (16 posts/step), 1 r (16), 2 hU (8), 3 B (8).
// Deps per step t:
//   ZR(i,g,t): U-side needs CB(i-1) >= 8(t+1)  [i>=1; i=0 reads x plain]
//              W-side + gate store need CB(i) >= 8t (prev ready + gate ack)
//   hU(i,t):   U-side needs CB(i-1) >= 8(t+1); store needs CB(i) >= 8t
//   B(i,t):    GEMV needs CR(i) >= 16(t+1) (implies prow ready via r's W-wait)
//              epilogue needs CZ(i) >= 16(t+1), CH(i) >= 8(t+1)
//              state-overwrite ack (slot held s_i(t-2); readers are A(i+1,t-2)):
//              CZ/CR(i+1) >= 16(t-1), CH(i+1) >= 8(t-1)   [in-layer readers implied]
// Publication: relaxed agent-scope atomic stores (write to IC), s_waitcnt(0) +
// barrier, thread0 atomicAdd. Consumption: relaxed poll; data read with relaxed
// AGENT atomic loads (coherent from IC, compiler-pipelined) -> NO acquire
// fence / L2 invalidation anywhere. x & weights use plain loads (read-only,
// L2 stays warm). State zeroed by host memset (never plain-stored in kernel).
#define CNT(f, i, g) ((f) + (((i) * 4 + (g)) * FLAG_STRIDE))
#define SPIN_CAP (1 << 20)     // ~0.3 s, then free-run via s_dead (no hang)

__device__ __forceinline__ void poll1(volatile int* sdead, int* c, int tgt) {
    int spins = 0;
    while (*sdead == 0 &&
           __hip_atomic_load(c, __ATOMIC_RELAXED, __HIP_MEMORY_SCOPE_AGENT) < tgt) {
        __builtin_amdgcn_s_sleep(1);
        if (++spins > SPIN_CAP) { *sdead = 1; break; }
    }
}

__device__ __forceinline__ void wg_post(int* cnt) {
    asm volatile("" ::: "memory");
    __builtin_amdgcn_s_waitcnt(0);   // own stores ack'd at coherence point
    __syncthreads();                 // all threads drained
    if (threadIdx.x == 0)
        atomicAdd(cnt, 1);           // device-scope, IC-level
}

__device__ __forceinline__ void pub_store(float* p, float v) {
    __hip_atomic_store(p, v, __ATOMIC_RELAXED, __HIP_MEMORY_SCOPE_AGENT);
}
__device__ __forceinline__ float2 ld2(const float* p) {   // 8B coherent load
    unsigned long long u = __hip_atomic_load((const unsigned long long*)p,
                              __ATOMIC_RELAXED, __HIP_MEMORY_SCOPE_AGENT);
    union { unsigned long long u; float2 f; } cv; cv.u = u; return cv.f;
}
__device__ __forceinline__ float ld1(const float* p) {    // 4B coherent load
    unsigned u = __hip_atomic_load((const unsigned*)p,
                    __ATOMIC_RELAXED, __HIP_MEMORY_SCOPE_AGENT);
    return __uint_as_float(u);
}

// WG roles (logical wg 0..191), TPB=512: b=tid&31, c=(tid>>5)&7, kh=tid>>8.
// Each thread accumulates its k-half; kh=1 dumps partials to LDS scratch,
// kh=0 combines + does the epilogue/stores.
//   wg   0..127: ZR. grp=wg>>4: i=grp>>1, g=grp&1; 32 cols; LDS = U|W
//   wg 128..159: hU. i=(wg-128)>>3; 64 cols; LDS = U2
//   wg 160..191: B.  i=(wg-160)>>3; 64 cols; LDS = W2
// LDS weight layouts (float4 units):
//   32-col: lds[(k*8 + c)*4]  = {M[k][c], M[k][c+8], M[k][c+16], M[k][c+24]}
//   64-col: lds[(k*16 + q)*4] = {M[k][q], M[k][q+16], M[k][q+32], M[k][q+48]}
// State/gate buffers b-major: slice[b*512 + col].

__global__ __launch_bounds__(TPB) void gru_wave(
    const float* __restrict__ x,    // [B,T,D]
    const float* __restrict__ Wp,   // [L,3,H,H]
    const float* __restrict__ Up,   // [L,3,D,H]
    float* __restrict__ out,        // [B,T,H]
    float* __restrict__ ws)
{
    extern __shared__ float lds[];  // 32768 weights + 2048 scratch
    __shared__ int s_dead;
    float* scratch = lds + 32768;

    const int bid = blockIdx.x;
    const int wg  = (bid & 7) * 24 + (bid >> 3);   // XCD-contiguous logical id
    const int tid = threadIdx.x;
    const int b   = tid & 31;
    const int c   = (tid >> 5) & 7;    // 0..7
    const int kh  = tid >> 8;          // k-half 0/1

    float* state = ws;                         // [L][2][B][H]
    float* zbuf  = state + LL * 2 * HB;        // [L][B][H]
    float* rbuf  = zbuf + LL * HB;
    float* hUbuf = rbuf + LL * HB;
    int*   flags = (int*)(ws + DATA_FLOATS);

    const bool isZR = wg < 128;
    const bool isHU = (wg >= 128) && (wg < 160);

    int iA = 0, gA = 0, col0 = 0, iB = 0, col0B = 0;
    if (isZR) { int grp = wg >> 4; iA = grp >> 1; gA = grp & 1; col0 = (wg & 15) * 32; }
    else if (isHU) { int w2 = wg - 128; iA = w2 >> 3; col0 = (w2 & 7) * 64; }
    else { int w3 = wg - 160; iB = w3 >> 3; col0B = (w3 & 7) * 64; }

    // ---- one-time weight staging into resident LDS (plain loads, L2) ----
    if (isZR) {
        const float* Um = Up + (size_t)(iA * 3 + gA) * DD * HH + col0;
        const float* Wm = Wp + (size_t)(iA * 3 + gA) * HH * HH + col0;
        for (int u = tid; u < 4096; u += TPB) {
            int k = u >> 3, cc = u & 7;
            const float* ur = Um + (size_t)k * HH + cc;
            *(float4*)&lds[u * 4] = make_float4(ur[0], ur[8], ur[16], ur[24]);
            const float* wr = Wm + (size_t)k * HH + cc;
            *(float4*)&lds[16384 + u * 4] = make_float4(wr[0], wr[8], wr[16], wr[24]);
        }
    } else {
        const float* Mm = isHU ? (Up + (size_t)(iA * 3 + 2) * DD * HH + col0)
                               : (Wp + (size_t)(iB * 3 + 2) * HH * HH + col0B);
        for (int u = tid; u < 8192; u += TPB) {
            int k = u >> 4, q = u & 15;
            const float* mr = Mm + (size_t)k * HH + q;
            *(float4*)&lds[u * 4] = make_float4(mr[0], mr[16], mr[32], mr[48]);
        }
    }
    if (tid == 0) s_dead = 0;
    __syncthreads();

    const int k0 = kh * 64, k1 = k0 + 64;   // k4 range for this thread

    if (isZR) {
        float* dst = (gA == 0 ? zbuf : rbuf) + (size_t)iA * HB + b * HH;
        int* cb_up = (iA > 0) ? CNT(flags, iA - 1, 3) : nullptr;
        int* cb_my = CNT(flags, iA, 3);
        int* c_my  = CNT(flags, iA, gA);
        for (int t = 0; t < TT; ++t) {
            float a0 = 0.f, a1 = 0.f, a2 = 0.f, a3 = 0.f;
            if (iA > 0) {
                if (tid == 0) poll1(&s_dead, cb_up, 8 * (t + 1));
                __syncthreads();
                const float* urow = state + (size_t)((iA - 1) * 2 + (t & 1)) * HB + b * HH;
                #pragma unroll 8
                for (int k4 = k0; k4 < k1; ++k4) {
                    float2 xa = ld2(&urow[k4 * 4]);
                    float2 xb = ld2(&urow[k4 * 4 + 2]);
                    float4 xi = make_float4(xa.x, xa.y, xb.x, xb.y);
                    #pragma unroll
                    for (int j = 0; j < 4; ++j) {
                        float xv = (&xi.x)[j];
                        float4 wv = *(const float4*)&lds[((k4 * 4 + j) * 8 + c) * 4];
                        a0 = fmaf(xv, wv.x, a0); a1 = fmaf(xv, wv.y, a1);
                        a2 = fmaf(xv, wv.z, a2); a3 = fmaf(xv, wv.w, a3);
                    }
                }
            } else {
                const float* urow = x + ((size_t)b * TT + t) * DD;
                #pragma unroll 8
                for (int k4 = k0; k4 < k1; ++k4) {
                    float4 xi = *(const float4*)&urow[k4 * 4];
                    #pragma unroll
                    for (int j = 0; j < 4; ++j) {
                        float xv = (&xi.x)[j];
                        float4 wv = *(const float4*)&lds[((k4 * 4 + j) * 8 + c) * 4];
                        a0 = fmaf(xv, wv.x, a0); a1 = fmaf(xv, wv.y, a1);
                        a2 = fmaf(xv, wv.z, a2); a3 = fmaf(xv, wv.w, a3);
                    }
                }
            }
            // prev-state ready + gate-buffer overwrite ack
            if (tid == 0) poll1(&s_dead, cb_my, 8 * t);
            __syncthreads();
            const float* prow = state + (size_t)(iA * 2 + ((t + 1) & 1)) * HB + b * HH;
            #pragma unroll 8
            for (int k4 = k0; k4 < k1; ++k4) {
                float2 pa = ld2(&prow[k4 * 4]);
                float2 pb = ld2(&prow[k4 * 4 + 2]);
                float4 pi = make_float4(pa.x, pa.y, pb.x, pb.y);
                #pragma unroll
                for (int j = 0; j < 4; ++j) {
                    float pv = (&pi.x)[j];
                    float4 wv = *(const float4*)&lds[16384 + ((k4 * 4 + j) * 8 + c) * 4];
                    a0 = fmaf(pv, wv.x, a0); a1 = fmaf(pv, wv.y, a1);
                    a2 = fmaf(pv, wv.z, a2); a3 = fmaf(pv, wv.w, a3);
                }
            }
            if (kh) *(float4*)&scratch[(tid - 256) * 4] = make_float4(a0, a1, a2, a3);
            __syncthreads();
            if (!kh) {
                float4 o = *(const float4*)&scratch[tid * 4];
                a0 += o.x; a1 += o.y; a2 += o.z; a3 += o.w;
                pub_store(&dst[col0 + c     ], 1.0f / (1.0f + __expf(-a0)));
                pub_store(&dst[col0 + c +  8], 1.0f / (1.0f + __expf(-a1)));
                pub_store(&dst[col0 + c + 16], 1.0f / (1.0f + __expf(-a2)));
                pub_store(&dst[col0 + c + 24], 1.0f / (1.0f + __expf(-a3)));
            }
            wg_post(c_my);
        }
    } else if (isHU) {
        float* hu = hUbuf + (size_t)iA * HB + b * HH;
        int* cb_up = (iA > 0) ? CNT(flags, iA - 1, 3) : nullptr;
        int* cb_my = CNT(flags, iA, 3);
        int* c_my  = CNT(flags, iA, 2);
        for (int t = 0; t < TT; ++t) {
            if (iA > 0) {
                if (tid == 0) poll1(&s_dead, cb_up, 8 * (t + 1));
                __syncthreads();
            }
            float a0 = 0.f, a1 = 0.f, a2 = 0.f, a3 = 0.f;
            float a4 = 0.f, a5 = 0.f, a6 = 0.f, a7 = 0.f;
            if (iA > 0) {
                const float* urow = state + (size_t)((iA - 1) * 2 + (t & 1)) * HB + b * HH;
                #pragma unroll 4
                for (int k4 = k0; k4 < k1; ++k4) {
                    float2 xa = ld2(&urow[k4 * 4]);
                    float2 xb = ld2(&urow[k4 * 4 + 2]);
                    float4 xi = make_float4(xa.x, xa.y, xb.x, xb.y);
                    #pragma unroll
                    for (int j = 0; j < 4; ++j) {
                        float xv = (&xi.x)[j];
                        float4 w0 = *(const float4*)&lds[((k4 * 4 + j) * 16 + c) * 4];
                        float4 w1 = *(const float4*)&lds[((k4 * 4 + j) * 16 + c + 8) * 4];
                        a0 = fmaf(xv, w0.x, a0); a1 = fmaf(xv, w0.y, a1);
                        a2 = fmaf(xv, w0.z, a2); a3 = fmaf(xv, w0.w, a3);
                        a4 = fmaf(xv, w1.x, a4); a5 = fmaf(xv, w1.y, a5);
                        a6 = fmaf(xv, w1.z, a6); a7 = fmaf(xv, w1.w, a7);
                    }
                }
            } else {
                const float* urow = x + ((size_t)b * TT + t) * DD;
                #pragma unroll 4
                for (int k4 = k0; k4 < k1; ++k4) {
                    float4 xi = *(const float4*)&urow[k4 * 4];
                    #pragma unroll
                    for (int j = 0; j < 4; ++j) {
                        float xv = (&xi.x)[j];
                        float4 w0 = *(const float4*)&lds[((k4 * 4 + j) * 16 + c) * 4];
                        float4 w1 = *(const float4*)&lds[((k4 * 4 + j) * 16 + c + 8) * 4];
                        a0 = fmaf(xv, w0.x, a0); a1 = fmaf(xv, w0.y, a1);
                        a2 = fmaf(xv, w0.z, a2); a3 = fmaf(xv, w0.w, a3);
                        a4 = fmaf(xv, w1.x, a4); a5 = fmaf(xv, w1.y, a5);
                        a6 = fmaf(xv, w1.z, a6); a7 = fmaf(xv, w1.w, a7);
                    }
                }
            }
            // store-ack (B consumed hU(t-1)) polled while kh=1 dumps partials
            if (tid == 0) poll1(&s_dead, cb_my, 8 * t);
            if (kh) {
                float* sp = &scratch[(tid - 256) * 8];
                sp[0] = a0; sp[1] = a1; sp[2] = a2; sp[3] = a3;
                sp[4] = a4; sp[5] = a5; sp[6] = a6; sp[7] = a7;
            }
            __syncthreads();
            if (!kh) {
                const float* sp = &scratch[tid * 8];
                pub_store(&hu[col0 + c     ], a0 + sp[0]);
                pub_store(&hu[col0 + c + 16], a1 + sp[1]);
                pub_store(&hu[col0 + c + 32], a2 + sp[2]);
                pub_store(&hu[col0 + c + 48], a3 + sp[3]);
                pub_store(&hu[col0 + c +  8], a4 + sp[4]);
                pub_store(&hu[col0 + c + 24], a5 + sp[5]);
                pub_store(&hu[col0 + c + 40], a6 + sp[6]);
                pub_store(&hu[col0 + c + 56], a7 + sp[7]);
            }
            wg_post(c_my);
        }
    } else {
        const float* rrow = rbuf + (size_t)iB * HB + b * HH;
        const float* hu = hUbuf + (size_t)iB * HB + b * HH;
        const float* zz = zbuf + (size_t)iB * HB + b * HH;
        int* c_my = CNT(flags, iB, 3);
        for (int t = 0; t < TT; ++t) {
            // r gates ready (implies prow complete via r's W-wait)
            if (tid == 0) poll1(&s_dead, CNT(flags, iB, 1), 16 * (t + 1));
            __syncthreads();
            const float* prow = state + (size_t)(iB * 2 + ((t + 1) & 1)) * HB + b * HH;
            float a0 = 0.f, a1 = 0.f, a2 = 0.f, a3 = 0.f;
            float a4 = 0.f, a5 = 0.f, a6 = 0.f, a7 = 0.f;
            #pragma unroll 4
            for (int k4 = k0; k4 < k1; ++k4) {
                float2 ra = ld2(&rrow[k4 * 4]);
                float2 rb = ld2(&rrow[k4 * 4 + 2]);
                float2 pa = ld2(&prow[k4 * 4]);
                float2 pb = ld2(&prow[k4 * 4 + 2]);
                float4 rp = make_float4(ra.x * pa.x, ra.y * pa.y,
                                        rb.x * pb.x, rb.y * pb.y);
                #pragma unroll
                for (int j = 0; j < 4; ++j) {
                    float v = (&rp.x)[j];
                    float4 w0 = *(const float4*)&lds[((k4 * 4 + j) * 16 + c) * 4];
                    float4 w1 = *(const float4*)&lds[((k4 * 4 + j) * 16 + c + 8) * 4];
                    a0 = fmaf(v, w0.x, a0); a1 = fmaf(v, w0.y, a1);
                    a2 = fmaf(v, w0.z, a2); a3 = fmaf(v, w0.w, a3);
                    a4 = fmaf(v, w1.x, a4); a5 = fmaf(v, w1.y, a5);
                    a6 = fmaf(v, w1.z, a6); a7 = fmaf(v, w1.w, a7);
                }
            }
            // Parallel polls (lane 0 of waves 0..4) while kh=1 dumps partials:
            //   z/hU of step t (epilogue inputs) + downstream overwrite ack
            //   (readers of s_i(t-2) = A(i+1,t-2): counters >= (t-1)-levels).
            if ((tid & 63) == 0) {
                const int w = tid >> 6;
                if (w == 0)      poll1(&s_dead, CNT(flags, iB, 0), 16 * (t + 1));
                else if (w == 1) poll1(&s_dead, CNT(flags, iB, 2), 8 * (t + 1));
                else if (iB < LL - 1) {
                    if (w == 2)      poll1(&s_dead, CNT(flags, iB + 1, 0), 16 * (t - 1));
                    else if (w == 3) poll1(&s_dead, CNT(flags, iB + 1, 1), 16 * (t - 1));
                    else if (w == 4) poll1(&s_dead, CNT(flags, iB + 1, 2), 8 * (t - 1));
                }
            }
            if (kh) {
                float* sp = &scratch[(tid - 256) * 8];
                sp[0] = a0; sp[1] = a1; sp[2] = a2; sp[3] = a3;
                sp[4] = a4; sp[5] = a5; sp[6] = a6; sp[7] = a7;
            }
            __syncthreads();
            if (!kh) {
                const float* sp = &scratch[tid * 8];
                float accv[8] = {a0 + sp[0], a1 + sp[1], a2 + sp[2], a3 + sp[3],
                                 a4 + sp[4], a5 + sp[5], a6 + sp[6], a7 + sp[7]};
                float* stNew = state + (size_t)(iB * 2 + (t & 1)) * HB + b * HH;
                const int coff[8] = {0, 16, 32, 48, 8, 24, 40, 56};
                #pragma unroll
                for (int j = 0; j < 8; ++j) {
                    const int col = col0B + c + coff[j];
                    float a2v = accv[j] + ld1(&hu[col]);
                    float h   = tanhf(a2v);
                    float zg  = ld1(&zz[col]);
                    float pv  = ld1(&prow[col]);
                    float s   = zg * (pv - h) + h;      // (1-z)*h + z*prev
                    pub_store(&stNew[col], s);
                    if (iB == LL - 1)
                        out[((size_t)b * TT + t) * HH + col] = s;
                }
            }
            wg_post(c_my);
        }
    }
}

extern "C" void kernel_launch(void* const* d_in, const int* in_sizes, int n_in,
                              void* d_out, int out_size, void* d_ws, size_t ws_size,
                              hipStream_t stream) {
    const float* x  = (const float*)d_in[0];  // [32,512,512]
    const float* Wp = (const float*)d_in[1];  // [4,3,512,512]
    const float* Up = (const float*)d_in[2];  // [4,3,512,512]
    float* out = (float*)d_out;
    float* ws  = (float*)d_ws;

    // Sentinel 1: workspace too small -> absmax ~8.5e37
    if (ws_size < WS_NEED_BYTES) {
        hipMemsetAsync(d_out, 0x7e, (size_t)out_size * sizeof(float), stream);
        return;
    }

    // Host-side zero of state (t=0 prev) and counters each call.
    // State is only ever written by IC-level atomic stores in the kernel, so
    // host memset keeps it free of dirty L2 aliases.
    hipMemsetAsync(ws, 0, (size_t)STATE_FLOATS * sizeof(float), stream);
    hipMemsetAsync(ws + DATA_FLOATS, 0, FLAGS_BYTES, stream);

    hipLaunchKernelGGL(gru_wave, dim3(NWG), dim3(TPB), LDS_BYTES, stream,
                       x, Wp, Up, out, ws);
    // Sentinel 2: launch rejected -> absmax ~3.4e38
    hipError_t err = hipGetLastError();
    if (err != hipSuccess)
        hipMemsetAsync(d_out, 0x7f, (size_t)out_size * sizeof(float), stream);
}